// Round 4
// baseline (324.311 us; speedup 1.0000x reference)
//
#include <hip/hip_runtime.h>
#include <hip/hip_bf16.h>
#include <cstdint>
#include <cstddef>

// Problem constants
#define BMC 32    // B*M
#define NNODE 1024
#define DIN 128
#define PPROJ 64
#define NCLUS 10
#define FOUT 128
#define KNB 10

typedef _Float16 half8 __attribute__((ext_vector_type(8)));
typedef float f32x4 __attribute__((ext_vector_type(4)));

// Inputs: fp32 (probe-confirmed). Output: fp32. Internals fp32 except:
//  - Z stored as fp16 split pair Zh/Zl (lo scaled x2048) for MFMA Gram
//  - Ek bf16 (overlays dead Zh/Zl region after k_topk)
// X_trans fp32 (16 MB) lives in d_out; k_final overwrites d_out with output.
static const size_t OFF_Z    = 0;          // words [0,1048576): Zh fp16; [1048576,2097152): Zl fp16
static const size_t OFF_SQ   = 2097152;    // 32,768     ||Z||^2 fp32
static const size_t OFF_HC   = 2129920;    // 327,680    softmax cluster H fp32
static const size_t OFF_IDX  = 2457600;    // 327,680    (int) knn indices
static const size_t OFF_CNT  = 2785280;    // 32,768     (int) edge in-degree  [ZEROED]
static const size_t OFF_FILL = 2818048;    // 32,768     (int) CSR fill ptrs   [ZEROED]
static const size_t OFF_EC   = 2850816;    // 40,960     cluster edge feats    [ZEROED]
static const size_t OFF_DCV  = 2891776;    // 320        cluster edge degrees  [ZEROED]
static const size_t OFF_OFFS = 2892096;    // 32,768     (int) CSR offsets
static const size_t OFF_ADJ  = 2924864;    // 327,680    (int) CSR adjacency
static const size_t OFF_FLAG = 3252544;    // 1          (int) input-dtype flag
static const size_t OFF_END  = 3252608;
static const size_t ZERO_N   = OFF_OFFS - OFF_CNT;

__device__ __forceinline__ float bfu(unsigned int lo16) {
    return __uint_as_float(lo16 << 16);
}
__device__ __forceinline__ float bfhi(unsigned int w) {
    return __uint_as_float(w & 0xffff0000u);
}
__device__ __forceinline__ float ldf(const void* p, size_t i, bool isbf) {
    return isbf ? bfu((unsigned int)((const unsigned short*)p)[i])
                : ((const float*)p)[i];
}
__device__ __forceinline__ unsigned short f2bf(float v) {
    __hip_bfloat16 h = __float2bfloat16(v);
    return *(unsigned short*)&h;
}

// --- top-k helpers: u64 sortable keys + compare-and-swap networks ---------
__device__ __forceinline__ unsigned long long mkkey(float v, int col) {
    unsigned int bits = __float_as_uint(v);
    unsigned int s = bits ^ (0x80000000u | (unsigned int)((int)bits >> 31));
    return ((unsigned long long)s << 32) | (unsigned int)col;
}
__device__ __forceinline__ void kcas(unsigned long long &a, unsigned long long &b) {
    bool c = b < a;
    unsigned long long t = c ? b : a;
    b = c ? a : b;
    a = t;
}
__device__ __forceinline__ void kmin(unsigned long long &a, unsigned long long b) {
    a = (b < a) ? b : a;
}

// ---------------------------------------------------------------------------
__global__ __launch_bounds__(256) void k_probe(const unsigned int* __restrict__ xw,
                                               int* __restrict__ flag) {
    __shared__ int red[256];
    int t = threadIdx.x;
    int cnt = 0;
    for (int i = t; i < 1024; i += 256) {
        float b = bfu(xw[i] & 0xffffu);
        float ab = fabsf(b);
        if (ab > 9.5e-7f && ab < 1.0e6f) cnt++;
    }
    red[t] = cnt;
    __syncthreads();
    for (int off = 128; off > 0; off >>= 1) {
        if (t < off) red[t] += red[t + off];
        __syncthreads();
    }
    if (t == 0) flag[0] = (red[0] >= 700) ? 1 : 0;
}

__global__ __launch_bounds__(256) void k_zero(float* __restrict__ p, int n) {
    int i = blockIdx.x * 256 + threadIdx.x;
    if (i < n) p[i] = 0.0f;
}

// ---------------------------------------------------------------------------
// Kernel 1 (R12): Z = x_flat @ Wp^T + b via fp16-split MFMA (was fp32 SIMD);
// sq = ||Z||^2 ; Hc = softmax(Z @ C^T) epilogue unchanged.
// Fragment convention identical to verified k_theta: A row = m16 (within
// 16-row tile), k = c32*32+quad*8; B col = m16; C/D col = m16 (lane&15),
// row = quad*4+reg. Z = Ah*Bh + (Al*Bh + Ah*Bl)/2048, ~2^-22 rel error.
// 4 waves: rh=wave>>1 (16-row half), ch=wave&1 (32-col half, 2 x 16).
// ---------------------------------------------------------------------------
__global__ __launch_bounds__(256) void k_proj(const void* __restrict__ x,
                                              const void* __restrict__ Wp,
                                              const void* __restrict__ Wpb,
                                              const void* __restrict__ Cm,
                                              const int* __restrict__ flag,
                                              _Float16* __restrict__ Zh,
                                              _Float16* __restrict__ Zl,
                                              float* __restrict__ sqv,
                                              float* __restrict__ Hc) {
    __shared__ __align__(16) _Float16 wps[2][64][72];
    __shared__ __align__(16) _Float16 xsh[2][32][72];
    __shared__ float zs[32][68];
    __shared__ float cs[10][64];

    const bool isbf = (flag[0] != 0);
    int tid = threadIdx.x;
    int bi  = blockIdx.x;
    int bm  = bi >> 5;
    int n0  = (bi & 31) << 5;
    int b   = bm >> 3, m = bm & 7;

    int lane = tid & 63, wave = tid >> 6;
    int m16 = lane & 15, quad = lane >> 4;
    int rh = wave >> 1, ch = wave & 1;

    for (int e = tid; e < 640; e += 256) cs[e >> 6][e & 63] = ldf(Cm, e, isbf);

    f32x4 aH[2], aX[2];
#pragma unroll
    for (int t = 0; t < 2; ++t) {
        aH[t] = (f32x4){0.f, 0.f, 0.f, 0.f};
        aX[t] = (f32x4){0.f, 0.f, 0.f, 0.f};
    }

    for (int kc = 0; kc < 2; ++kc) {
        __syncthreads();
        for (int e = tid; e < 4096; e += 256) {
            int p = e >> 6, dk = e & 63;
            float v = ldf(Wp, (size_t)p * 128 + kc * 64 + dk, isbf);
            _Float16 h = (_Float16)v;
            wps[0][p][dk] = h;
            wps[1][p][dk] = (_Float16)((v - (float)h) * 2048.0f);
        }
        for (int e = tid; e < 2048; e += 256) {
            int r = e >> 6, dk = e & 63;
            float v = ldf(x, (((size_t)b * NNODE + n0 + r) * 8 + m) * DIN + kc * 64 + dk, isbf);
            _Float16 h = (_Float16)v;
            xsh[0][r][dk] = h;
            xsh[1][r][dk] = (_Float16)((v - (float)h) * 2048.0f);
        }
        __syncthreads();
#pragma unroll
        for (int c32 = 0; c32 < 2; ++c32) {
            half8 Ah = *(const half8*)&xsh[0][rh * 16 + m16][c32 * 32 + quad * 8];
            half8 Al = *(const half8*)&xsh[1][rh * 16 + m16][c32 * 32 + quad * 8];
#pragma unroll
            for (int t = 0; t < 2; ++t) {
                int p = ch * 32 + t * 16 + m16;
                half8 Bh = *(const half8*)&wps[0][p][c32 * 32 + quad * 8];
                half8 Bl = *(const half8*)&wps[1][p][c32 * 32 + quad * 8];
                aH[t] = __builtin_amdgcn_mfma_f32_16x16x32_f16(Ah, Bh, aH[t], 0, 0, 0);
                aX[t] = __builtin_amdgcn_mfma_f32_16x16x32_f16(Al, Bh, aX[t], 0, 0, 0);
                aX[t] = __builtin_amdgcn_mfma_f32_16x16x32_f16(Ah, Bl, aX[t], 0, 0, 0);
            }
        }
    }

#pragma unroll
    for (int t = 0; t < 2; ++t) {
        int p = ch * 32 + t * 16 + m16;
        float bias = ldf(Wpb, p, isbf);
#pragma unroll
        for (int r = 0; r < 4; ++r) {
            int row = rh * 16 + quad * 4 + r;
            float v = aH[t][r] + aX[t][r] * (1.0f / 2048.0f) + bias;
            zs[row][p] = v;
            size_t off = ((size_t)bm * NNODE + n0 + row) * 64 + p;
            _Float16 h = (_Float16)v;
            Zh[off] = h;
            Zl[off] = (_Float16)((v - (float)h) * 2048.0f);
        }
    }
    __syncthreads();

    int row = tid >> 3, slot = tid & 7;
    int d0 = slot * 8;
    float sp = 0.f;
#pragma unroll
    for (int dd = 0; dd < 8; ++dd) { float z = zs[row][d0+dd]; sp += z * z; }
#pragma unroll
    for (int mm = 1; mm < 8; mm <<= 1) sp += __shfl_xor(sp, mm, 8);
    size_t g = (size_t)bm * NNODE + n0 + row;
    if (slot == 0) sqv[g] = sp;

    float sc[10];
#pragma unroll
    for (int c = 0; c < 10; ++c) {
        float pa = 0.f;
#pragma unroll
        for (int dd = 0; dd < 8; ++dd) pa += zs[row][d0+dd] * cs[c][d0+dd];
#pragma unroll
        for (int mm = 1; mm < 8; mm <<= 1) pa += __shfl_xor(pa, mm, 8);
        sc[c] = pa;
    }
    float mx = sc[0];
#pragma unroll
    for (int c = 1; c < 10; ++c) mx = fmaxf(mx, sc[c]);
    float ssum = 0.f;
#pragma unroll
    for (int c = 0; c < 10; ++c) { sc[c] = expf(sc[c] - mx); ssum += sc[c]; }
    float inv = 1.0f / ssum;
#pragma unroll
    for (int c = 0; c < 10; ++c)
        if ((c & 7) == slot) Hc[g * 10 + c] = sc[c] * inv;
}

// ---------------------------------------------------------------------------
// Kernel 2 (R12): X_trans = x_flat @ Theta^T + b via fp16-split MFMA,
// now FUSED with the cluster-edge partial (old k_clus): after the MFMA
// loop the Theta LDS region is dead; overlay a f32 copy of the 32x128 Xt
// tile + the 32x10 Hc slice, accumulate Ec partial (32x5 FMA/thread) and
// Dcv, atomicAdd to global. Kills the 16 MB Xt re-read of k_clus.
// ---------------------------------------------------------------------------
__global__ __launch_bounds__(256) void k_theta(const void* __restrict__ x,
                                               const void* __restrict__ Th,
                                               const void* __restrict__ Thb,
                                               const int* __restrict__ flag,
                                               const float* __restrict__ Hc,
                                               float* __restrict__ Xt,
                                               float* __restrict__ Ec,
                                               float* __restrict__ Dcv) {
    __shared__ __align__(16) char smem[46080];
    _Float16* ths0 = (_Float16*)smem;            // [128][72]
    _Float16* ths1 = ths0 + 128 * 72;            // [128][72]
    _Float16* xs0  = ths1 + 128 * 72;            // [32][72]
    _Float16* xs1  = xs0 + 32 * 72;              // [32][72]
    float* zs  = (float*)smem;                   // overlay [32][132] (after MFMA)
    float* hcs = (float*)smem + 32 * 132;        // overlay [32][12]

    const bool isbf = (flag[0] != 0);
    int tid = threadIdx.x;
    int bi  = blockIdx.x;
    int bm  = bi >> 5;
    int n0  = (bi & 31) << 5;
    int b   = bm >> 3, m = bm & 7;

    int lane = tid & 63, wave = tid >> 6;
    int m16 = lane & 15, quad = lane >> 4;
    int rh = wave >> 1, ch = wave & 1;   // 2x2 wave grid: rows rh*16, cols ch*64

    f32x4 aH[4], aX[4];
#pragma unroll
    for (int t = 0; t < 4; ++t) {
        aH[t] = (f32x4){0.f, 0.f, 0.f, 0.f};
        aX[t] = (f32x4){0.f, 0.f, 0.f, 0.f};
    }

    for (int kc = 0; kc < 2; ++kc) {
        __syncthreads();
        for (int e = tid; e < 8192; e += 256) {
            int f = e >> 6, dk = e & 63;
            float v = ldf(Th, (size_t)f * 128 + kc * 64 + dk, isbf);
            _Float16 h = (_Float16)v;
            ths0[f * 72 + dk] = h;
            ths1[f * 72 + dk] = (_Float16)((v - (float)h) * 2048.0f);
        }
        for (int e = tid; e < 2048; e += 256) {
            int r = e >> 6, dk = e & 63;
            float v = ldf(x, (((size_t)b * NNODE + n0 + r) * 8 + m) * DIN + kc * 64 + dk, isbf);
            _Float16 h = (_Float16)v;
            xs0[r * 72 + dk] = h;
            xs1[r * 72 + dk] = (_Float16)((v - (float)h) * 2048.0f);
        }
        __syncthreads();
#pragma unroll
        for (int c32 = 0; c32 < 2; ++c32) {
            half8 Ah = *(const half8*)&xs0[(rh * 16 + m16) * 72 + c32 * 32 + quad * 8];
            half8 Al = *(const half8*)&xs1[(rh * 16 + m16) * 72 + c32 * 32 + quad * 8];
#pragma unroll
            for (int t = 0; t < 4; ++t) {
                int f = ch * 64 + t * 16 + m16;
                half8 Bh = *(const half8*)&ths0[f * 72 + c32 * 32 + quad * 8];
                half8 Bl = *(const half8*)&ths1[f * 72 + c32 * 32 + quad * 8];
                aH[t] = __builtin_amdgcn_mfma_f32_16x16x32_f16(Ah, Bh, aH[t], 0, 0, 0);
                aX[t] = __builtin_amdgcn_mfma_f32_16x16x32_f16(Al, Bh, aX[t], 0, 0, 0);
                aX[t] = __builtin_amdgcn_mfma_f32_16x16x32_f16(Ah, Bl, aX[t], 0, 0, 0);
            }
        }
    }

    __syncthreads();   // all LDS frag reads done -> safe to overlay zs/hcs
#pragma unroll
    for (int t = 0; t < 4; ++t) {
        int f = ch * 64 + t * 16 + m16;
        float bias = ldf(Thb, f, isbf);
        size_t rb = (size_t)bm * NNODE + n0 + rh * 16 + quad * 4;
#pragma unroll
        for (int r = 0; r < 4; ++r) {
            float v = aH[t][r] + aX[t][r] * (1.0f / 2048.0f) + bias;
            Xt[(rb + r) * 128 + f] = v;
            zs[(rh * 16 + quad * 4 + r) * 132 + f] = v;
        }
    }
    for (int e = tid; e < 320; e += 256) {
        int r = e / 10, c = e - r * 10;
        hcs[r * 12 + c] = Hc[((size_t)bm * NNODE + n0 + r) * 10 + c];
    }
    __syncthreads();

    int f = tid & 127, h2 = tid >> 7, c0 = h2 * 5;
    float ca0 = 0.f, ca1 = 0.f, ca2 = 0.f, ca3 = 0.f, ca4 = 0.f;
#pragma unroll 4
    for (int n = 0; n < 32; ++n) {
        float xv = zs[n * 132 + f];
        ca0 = fmaf(hcs[n * 12 + c0 + 0], xv, ca0);
        ca1 = fmaf(hcs[n * 12 + c0 + 1], xv, ca1);
        ca2 = fmaf(hcs[n * 12 + c0 + 2], xv, ca2);
        ca3 = fmaf(hcs[n * 12 + c0 + 3], xv, ca3);
        ca4 = fmaf(hcs[n * 12 + c0 + 4], xv, ca4);
    }
    float* ecb = Ec + ((size_t)bm * 10 + c0) * 128 + f;
    atomicAdd(ecb + 0 * 128, ca0);
    atomicAdd(ecb + 1 * 128, ca1);
    atomicAdd(ecb + 2 * 128, ca2);
    atomicAdd(ecb + 3 * 128, ca3);
    atomicAdd(ecb + 4 * 128, ca4);
    if (f == 0) {
#pragma unroll
        for (int j = 0; j < 5; ++j) {
            float dj = 0.f;
            for (int n = 0; n < 32; ++n) dj += hcs[n * 12 + c0 + j];
            atomicAdd(&Dcv[bm * 10 + c0 + j], dj);
        }
    }
}

// ---------------------------------------------------------------------------
// Kernel 3 (R12): fused Gram + top-K, 32 rows/block.
// (a) XCD-affinity swizzle: swz=(bi&7)*128+(bi>>3) -> each XCD serves 4 bm
//     slabs (1 MB Zh/Zl working set < 4 MB L2).
// (b) T14 register prefetch: per tile {ds_write staged regs -> bar ->
//     MFMA+ST -> issue tile t+1 global loads -> bar -> selection}; HBM/L2
//     latency hides under the ~220-inst selection VALU phase. 2 barriers
//     per tile preserved (hazards audited: BH/BL(t) write races only with
//     selection(t-1) which reads ST only; ST(t) writes behind bar 1).
// ---------------------------------------------------------------------------
__global__ __launch_bounds__(256) void k_topk(const _Float16* __restrict__ Zh,
                                              const _Float16* __restrict__ Zl,
                                              const float* __restrict__ sqv,
                                              int* __restrict__ idxo,
                                              int* __restrict__ cnt) {
    __shared__ __align__(16) _Float16 BH[64 * 72];
    __shared__ __align__(16) _Float16 BL[64 * 72];
    __shared__ float    ST[64 * 36];
    __shared__ float    sqt[64];

    int tid = threadIdx.x;
    int bi  = blockIdx.x;
    int swb = (bi & 7) * 128 + (bi >> 3);   // XCD-affinity bijection (1024 % 8 == 0)
    int bm  = swb >> 5;
    int n0  = (swb & 31) << 5;
    const _Float16* Zhb = Zh + (size_t)bm * NNODE * 64;
    const _Float16* Zlb = Zl + (size_t)bm * NNODE * 64;

    int lane = tid & 63, wave = tid >> 6;
    int m16 = lane & 15, quad = lane >> 4;

    half8 ah0, ah1, al0, al1, ah0b, ah1b, al0b, al1b;
    {
        size_t ab = (size_t)(n0 + m16) * 64 + quad * 8;
        ah0 = *(const half8*)(Zhb + ab);
        ah1 = *(const half8*)(Zhb + ab + 32);
        al0 = *(const half8*)(Zlb + ab);
        al1 = *(const half8*)(Zlb + ab + 32);
        size_t ab2 = ab + 16 * 64;
        ah0b = *(const half8*)(Zhb + ab2);
        ah1b = *(const half8*)(Zhb + ab2 + 32);
        al0b = *(const half8*)(Zlb + ab2);
        al1b = *(const half8*)(Zlb + ab2 + 32);
    }

    unsigned long long keys[10];
#pragma unroll
    for (int j = 0; j < 10; ++j) keys[j] = ~0ULL;

    int srow  = tid >> 3;    // 0..31: this thread's row
    int sslot = tid & 7;     // 8 threads per row

    // staging coords (fixed per thread): 4x uint4 per tile
    int c0s = tid >> 3, k0s = tid & 7;
    int c1s = c0s + 32;
    uint4 rH0, rL0, rH1, rL1;
    float rsq = 0.f;
    {
        rH0 = *(const uint4*)(Zhb + (size_t)c0s * 64 + k0s * 8);
        rL0 = *(const uint4*)(Zlb + (size_t)c0s * 64 + k0s * 8);
        rH1 = *(const uint4*)(Zhb + (size_t)c1s * 64 + k0s * 8);
        rL1 = *(const uint4*)(Zlb + (size_t)c1s * 64 + k0s * 8);
        if (tid < 64) rsq = sqv[(size_t)bm * NNODE + tid];
    }

    for (int t = 0; t < 16; ++t) {
        int j0 = t << 6;
        *(uint4*)&BH[c0s * 72 + k0s * 8] = rH0;
        *(uint4*)&BL[c0s * 72 + k0s * 8] = rL0;
        *(uint4*)&BH[c1s * 72 + k0s * 8] = rH1;
        *(uint4*)&BL[c1s * 72 + k0s * 8] = rL1;
        if (tid < 64) sqt[tid] = rsq;
        __syncthreads();

        {
            int cl = wave * 16 + m16;
            const _Float16* pb = &BH[cl * 72 + quad * 8];
            const _Float16* pl = &BL[cl * 72 + quad * 8];
            half8 bh0 = *(const half8*)pb;
            half8 bh1 = *(const half8*)(pb + 32);
            half8 bl0 = *(const half8*)pl;
            half8 bl1 = *(const half8*)(pl + 32);
            float sqc = sqt[cl];

            f32x4 acc  = {0.f, 0.f, 0.f, 0.f};
            f32x4 accx = {0.f, 0.f, 0.f, 0.f};
            acc  = __builtin_amdgcn_mfma_f32_16x16x32_f16(ah0, bh0, acc, 0, 0, 0);
            acc  = __builtin_amdgcn_mfma_f32_16x16x32_f16(ah1, bh1, acc, 0, 0, 0);
            accx = __builtin_amdgcn_mfma_f32_16x16x32_f16(al0, bh0, accx, 0, 0, 0);
            accx = __builtin_amdgcn_mfma_f32_16x16x32_f16(ah0, bl0, accx, 0, 0, 0);
            accx = __builtin_amdgcn_mfma_f32_16x16x32_f16(al1, bh1, accx, 0, 0, 0);
            accx = __builtin_amdgcn_mfma_f32_16x16x32_f16(ah1, bl1, accx, 0, 0, 0);
            f32x4 sc;
#pragma unroll
            for (int r = 0; r < 4; ++r) {
                float g = acc[r] + accx[r] * (1.0f / 2048.0f);
                sc[r] = fmaf(-2.0f, g, sqc);
            }
            *(f32x4*)&ST[cl * 36 + quad * 4] = sc;

            f32x4 accB  = {0.f, 0.f, 0.f, 0.f};
            f32x4 accxB = {0.f, 0.f, 0.f, 0.f};
            accB  = __builtin_amdgcn_mfma_f32_16x16x32_f16(ah0b, bh0, accB, 0, 0, 0);
            accB  = __builtin_amdgcn_mfma_f32_16x16x32_f16(ah1b, bh1, accB, 0, 0, 0);
            accxB = __builtin_amdgcn_mfma_f32_16x16x32_f16(al0b, bh0, accxB, 0, 0, 0);
            accxB = __builtin_amdgcn_mfma_f32_16x16x32_f16(ah0b, bl0, accxB, 0, 0, 0);
            accxB = __builtin_amdgcn_mfma_f32_16x16x32_f16(al1b, bh1, accxB, 0, 0, 0);
            accxB = __builtin_amdgcn_mfma_f32_16x16x32_f16(ah1b, bl1, accxB, 0, 0, 0);
#pragma unroll
            for (int r = 0; r < 4; ++r) {
                float g = accB[r] + accxB[r] * (1.0f / 2048.0f);
                sc[r] = fmaf(-2.0f, g, sqc);
            }
            *(f32x4*)&ST[cl * 36 + 16 + quad * 4] = sc;
        }

        if (t < 15) {   // prefetch tile t+1 into regs; latency hides under selection
            int j1 = (t + 1) << 6;
            rH0 = *(const uint4*)(Zhb + (size_t)(j1 + c0s) * 64 + k0s * 8);
            rL0 = *(const uint4*)(Zlb + (size_t)(j1 + c0s) * 64 + k0s * 8);
            rH1 = *(const uint4*)(Zhb + (size_t)(j1 + c1s) * 64 + k0s * 8);
            rL1 = *(const uint4*)(Zlb + (size_t)(j1 + c1s) * 64 + k0s * 8);
            if (tid < 64) rsq = sqv[(size_t)bm * NNODE + j1 + tid];
        }
        __syncthreads();

        unsigned long long b0 = mkkey(ST[(sslot     ) * 36 + srow], j0 + sslot);
        unsigned long long b1 = mkkey(ST[(sslot +  8) * 36 + srow], j0 + sslot + 8);
        unsigned long long b2 = mkkey(ST[(sslot + 16) * 36 + srow], j0 + sslot + 16);
        unsigned long long b3 = mkkey(ST[(sslot + 24) * 36 + srow], j0 + sslot + 24);
        unsigned long long b4 = mkkey(ST[(sslot + 32) * 36 + srow], j0 + sslot + 32);
        unsigned long long b5 = mkkey(ST[(sslot + 40) * 36 + srow], j0 + sslot + 40);
        unsigned long long b6 = mkkey(ST[(sslot + 48) * 36 + srow], j0 + sslot + 48);
        unsigned long long b7 = mkkey(ST[(sslot + 56) * 36 + srow], j0 + sslot + 56);

        // --- sort-8 ascending: Batcher odd-even mergesort (19 CAS, depth 6)
        kcas(b0, b1); kcas(b2, b3); kcas(b4, b5); kcas(b6, b7);
        kcas(b0, b2); kcas(b1, b3); kcas(b4, b6); kcas(b5, b7);
        kcas(b1, b2); kcas(b5, b6);
        kcas(b0, b4); kcas(b1, b5); kcas(b2, b6); kcas(b3, b7);
        kcas(b2, b4); kcas(b3, b5);
        kcas(b1, b2); kcas(b3, b4); kcas(b5, b6);

        // --- lowest-10 of (sorted keys[10]) U (sorted b0..b7)
        kmin(keys[2], b7); kmin(keys[3], b6); kmin(keys[4], b5); kmin(keys[5], b4);
        kmin(keys[6], b3); kmin(keys[7], b2); kmin(keys[8], b1); kmin(keys[9], b0);

        // --- re-sort: bitonic merge-16 restricted to 10 (15 CAS, depth 4)
        kcas(keys[0], keys[8]); kcas(keys[1], keys[9]);
        kcas(keys[2], keys[6]); kcas(keys[3], keys[7]);
        kcas(keys[4], keys[8]); kcas(keys[5], keys[9]);
        kcas(keys[2], keys[4]); kcas(keys[3], keys[5]);
        kcas(keys[6], keys[8]); kcas(keys[7], keys[9]);
        kcas(keys[0], keys[1]); kcas(keys[2], keys[3]);
        kcas(keys[4], keys[5]); kcas(keys[6], keys[7]); kcas(keys[8], keys[9]);
    }

    size_t gr = (size_t)bm * NNODE + n0 + srow;
    for (int it = 0; it < 10; ++it) {
        unsigned long long mine = keys[0];
        unsigned long long best = mine;
#pragma unroll
        for (int mm = 1; mm < 8; mm <<= 1) {
            unsigned long long o = __shfl_xor(best, mm, 8);
            if (o < best) best = o;
        }
        if (best == mine) {
#pragma unroll
            for (int j = 0; j < 9; ++j) keys[j] = keys[j+1];
            keys[9] = ~0ULL;
            int col = (int)(best & 0xFFFFFFFFu);
            idxo[gr * KNB + it] = col;
            atomicAdd(&cnt[bm * NNODE + col], 1);
        }
    }
}

// ---------------------------------------------------------------------------
// CSR build (unchanged)
// ---------------------------------------------------------------------------
__global__ __launch_bounds__(256) void k_scan(const int* __restrict__ cnt,
                                              int* __restrict__ offs) {
    __shared__ int part[256];
    int bm = blockIdx.x, t = threadIdx.x;
    int base = bm * 1024 + t * 4;
    int c0 = cnt[base], c1 = cnt[base+1], c2 = cnt[base+2], c3 = cnt[base+3];
    int ps = c0 + c1 + c2 + c3;
    part[t] = ps;
    __syncthreads();
    for (int off = 1; off < 256; off <<= 1) {
        int add = (t >= off) ? part[t - off] : 0;
        __syncthreads();
        part[t] += add;
        __syncthreads();
    }
    int e0 = part[t] - ps;
    int gb = bm * (NNODE * KNB);
    offs[base]   = gb + e0;
    offs[base+1] = gb + e0 + c0;
    offs[base+2] = gb + e0 + c0 + c1;
    offs[base+3] = gb + e0 + c0 + c1 + c2;
}

__global__ __launch_bounds__(256) void k_fill(const int* __restrict__ idxb,
                                              const int* __restrict__ offs,
                                              int* __restrict__ fill,
                                              int* __restrict__ adj) {
    int i = blockIdx.x * 256 + threadIdx.x;
    int g = i / 10;
    int bm = g >> 10;
    int e  = idxb[i];
    int eg = (bm << 10) + e;
    int pos = atomicAdd(&fill[eg], 1);
    adj[offs[eg] + pos] = g;
}

// ---------------------------------------------------------------------------
// kNN edge gather v3 (R11, unchanged): XCD swizzle + 16-wide batch gather.
// ---------------------------------------------------------------------------
__global__ __launch_bounds__(256) void k_edge(const float* __restrict__ Xt,
                                              const int* __restrict__ offs,
                                              const int* __restrict__ cnt,
                                              const int* __restrict__ adj,
                                              unsigned short* __restrict__ Ek) {
    int tid = threadIdx.x;
    int bi  = blockIdx.x;
    int swz = (bi & 7) * 512 + (bi >> 3);
    int e = swz * 8 + (tid >> 5);
    int l = tid & 31;
    int start = offs[e];
    int num = cnt[e];
    float4 acc = {0.f, 0.f, 0.f, 0.f};
    if (num > 0) {
        int nm1 = num - 1;
        int gidx[16];
#pragma unroll
        for (int j = 0; j < 16; ++j) {
            int jj = (j < nm1) ? j : nm1;
            gidx[j] = adj[start + jj];
        }
#pragma unroll
        for (int j = 0; j < 16; ++j) {
            float4 a = *(const float4*)(Xt + (size_t)gidx[j] * 128 + l * 4);
            float w = (j < num) ? 1.0f : 0.0f;
            acc.x = fmaf(w, a.x, acc.x);
            acc.y = fmaf(w, a.y, acc.y);
            acc.z = fmaf(w, a.z, acc.z);
            acc.w = fmaf(w, a.w, acc.w);
        }
        int i = 16;
        for (; i + 1 < num; i += 2) {
            int g0 = adj[start + i];
            int g1 = adj[start + i + 1];
            float4 a = *(const float4*)(Xt + (size_t)g0 * 128 + l * 4);
            float4 b = *(const float4*)(Xt + (size_t)g1 * 128 + l * 4);
            acc.x += a.x + b.x; acc.y += a.y + b.y;
            acc.z += a.z + b.z; acc.w += a.w + b.w;
        }
        if (i < num) {
            int g0 = adj[start + i];
            float4 a = *(const float4*)(Xt + (size_t)g0 * 128 + l * 4);
            acc.x += a.x; acc.y += a.y; acc.z += a.z; acc.w += a.w;
        }
    }
    float scale = (num > 0) ? 1.0f / (float)num : 0.0f;
    ushort4 o;
    o.x = f2bf(acc.x * scale);
    o.y = f2bf(acc.y * scale);
    o.z = f2bf(acc.z * scale);
    o.w = f2bf(acc.w * scale);
    *(ushort4*)(Ek + (size_t)e * 128 + l * 4) = o;
}

__global__ __launch_bounds__(256) void k_escale(float* __restrict__ Ec,
                                                const float* __restrict__ Dcv) {
    int i = blockIdx.x * 256 + threadIdx.x;
    float d = Dcv[i >> 7];
    Ec[i] = (d > 0.f) ? Ec[i] / d : 0.f;
}

// ---------------------------------------------------------------------------
// Final v3 (R11, unchanged): 32 threads/node, XCD swizzle.
// ---------------------------------------------------------------------------
__global__ __launch_bounds__(256) void k_final(const unsigned short* __restrict__ Ek,
                                               const float* __restrict__ Ec,
                                               const float* __restrict__ Hc,
                                               const int* __restrict__ idxb,
                                               float* __restrict__ out) {
    int tid = threadIdx.x;
    int bi  = blockIdx.x;
    int swz = (bi & 7) * 512 + (bi >> 3);
    int g = swz * 8 + (tid >> 5);
    int l = tid & 31;
    int bm = g >> 10, n = g & 1023;
    const int* ip = idxb + (size_t)g * 10;
    const unsigned short* ekb = Ek + ((size_t)bm << 10) * 128 + l * 4;

    float4 acc = {0.f, 0.f, 0.f, 0.f};
#pragma unroll
    for (int k = 0; k < 10; k += 2) {
        int e0 = ip[k], e1 = ip[k + 1];
        ushort4 u0 = *(const ushort4*)(ekb + (size_t)e0 * 128);
        ushort4 u1 = *(const ushort4*)(ekb + (size_t)e1 * 128);
        acc.x += bfu(u0.x) + bfu(u1.x);
        acc.y += bfu(u0.y) + bfu(u1.y);
        acc.z += bfu(u0.z) + bfu(u1.z);
        acc.w += bfu(u0.w) + bfu(u1.w);
    }
    const float* hp  = Hc + (size_t)g * 10;
    const float* ecp = Ec + (size_t)bm * 10 * 128 + l * 4;
#pragma unroll
    for (int c = 0; c < 10; ++c) {
        float hv = hp[c];
        float4 ec = *(const float4*)(ecp + c * 128);
        acc.x += hv * ec.x; acc.y += hv * ec.y;
        acc.z += hv * ec.z; acc.w += hv * ec.w;
    }
    float4 r;
    r.x = acc.x * (1.0f / 11.0f);
    r.y = acc.y * (1.0f / 11.0f);
    r.z = acc.z * (1.0f / 11.0f);
    r.w = acc.w * (1.0f / 11.0f);
    r.x = (r.x > 0.f) ? r.x : expm1f(r.x);
    r.y = (r.y > 0.f) ? r.y : expm1f(r.y);
    r.z = (r.z > 0.f) ? r.z : expm1f(r.z);
    r.w = (r.w > 0.f) ? r.w : expm1f(r.w);
    int b = bm >> 3, m = bm & 7;
    *(float4*)(out + (((size_t)b * NNODE + n) * 8 + m) * 128 + l * 4) = r;
}

// ---------------------------------------------------------------------------
extern "C" void kernel_launch(void* const* d_in, const int* in_sizes, int n_in,
                              void* d_out, int out_size, void* d_ws, size_t ws_size,
                              hipStream_t stream) {
    const void* x   = d_in[0];
    const void* Wp  = d_in[1];
    const void* Wpb = d_in[2];
    const void* Cm  = d_in[3];
    const void* Th  = d_in[4];
    const void* Thb = d_in[5];
    float* ws = (float*)d_ws;

    if (ws_size < OFF_END * sizeof(float)) return;

    _Float16* Zh = (_Float16*)(ws + OFF_Z);
    _Float16* Zl = (_Float16*)(ws + OFF_Z + 1048576);
    float* sqv  = ws + OFF_SQ;
    float* Hc   = ws + OFF_HC;
    int*   idxb = (int*)(ws + OFF_IDX);
    int*   cnt  = (int*)(ws + OFF_CNT);
    int*   fill = (int*)(ws + OFF_FILL);
    float* Ec   = ws + OFF_EC;
    float* Dcv  = ws + OFF_DCV;
    int*   offs = (int*)(ws + OFF_OFFS);
    int*   adj  = (int*)(ws + OFF_ADJ);
    int*   flag = (int*)(ws + OFF_FLAG);
    unsigned short* Ek = (unsigned short*)(ws + OFF_Z);  // overlays dead Zh/Zl
    float* Xt  = (float*)d_out;
    float* out = (float*)d_out;

    k_probe <<<1, 256, 0, stream>>>((const unsigned int*)x, flag);
    k_zero  <<<(int)((ZERO_N + 255) / 256), 256, 0, stream>>>(ws + OFF_CNT, (int)ZERO_N);
    k_proj  <<<1024, 256, 0, stream>>>(x, Wp, Wpb, Cm, flag, Zh, Zl, sqv, Hc);
    k_topk  <<<1024, 256, 0, stream>>>(Zh, Zl, sqv, idxb, cnt);
    k_scan  <<<32,   256, 0, stream>>>(cnt, offs);
    k_fill  <<<1280, 256, 0, stream>>>(idxb, offs, fill, adj);
    k_theta <<<1024, 256, 0, stream>>>(x, Th, Thb, flag, Hc, Xt, Ec, Dcv);
    k_edge  <<<4096, 256, 0, stream>>>(Xt, offs, cnt, adj, Ek);
    k_escale<<<160,  256, 0, stream>>>(Ec, Dcv);
    k_final <<<4096, 256, 0, stream>>>(Ek, Ec, Hc, idxb, out);
}

// Round 5
// 268.583 us; speedup vs baseline: 1.2075x; 1.2075x over previous
//
#include <hip/hip_runtime.h>
#include <hip/hip_bf16.h>
#include <cstdint>
#include <cstddef>

// Problem constants
#define BMC 32    // B*M
#define NNODE 1024
#define DIN 128
#define PPROJ 64
#define NCLUS 10
#define FOUT 128
#define KNB 10

typedef _Float16 half8 __attribute__((ext_vector_type(8)));
typedef float f32x4 __attribute__((ext_vector_type(4)));

// Inputs: fp32 (probe-confirmed). Output: fp32. Internals fp32 except:
//  - Z stored as fp16 split pair Zh/Zl (lo scaled x2048) for MFMA Gram
//  - Ek bf16 (overlays dead Zh/Zl region after k_topk)
// X_trans fp32 (16 MB) lives in d_out; k_final overwrites d_out with output.
static const size_t OFF_Z    = 0;          // words [0,1048576): Zh fp16; [1048576,2097152): Zl fp16
static const size_t OFF_SQ   = 2097152;    // 32,768     ||Z||^2 fp32
static const size_t OFF_HC   = 2129920;    // 327,680    softmax cluster H fp32
static const size_t OFF_IDX  = 2457600;    // 327,680    (int) knn indices
static const size_t OFF_CNT  = 2785280;    // 32,768     (int) edge in-degree  [ZEROED early]
static const size_t OFF_FILL = 2818048;    // 32,768     (int) CSR fill ptrs   [ZEROED early]
static const size_t OFF_EC   = 2850816;    // 40,960     cluster edge feats    [ZEROED after k_theta]
static const size_t OFF_DCV  = 2891776;    // 320        cluster edge degrees  [ZEROED after k_theta]
static const size_t OFF_OFFS = 2892096;    // 32,768     (int) CSR offsets
static const size_t OFF_ADJ  = 2924864;    // 327,680    (int) CSR adjacency
static const size_t OFF_FLAG = 3252544;    // 1          (int) input-dtype flag
static const size_t OFF_END  = 3252608;
// Pre-split fp16 weights OVERLAY the Ec region (dead until after k_theta):
static const size_t OFF_WPH  = OFF_EC;           // 4096 words  (8192 fp16)
static const size_t OFF_WPL  = OFF_EC +  4096;   // 4096 words
static const size_t OFF_THH  = OFF_EC +  8192;   // 8192 words  (16384 fp16)
static const size_t OFF_THL  = OFF_EC + 16384;   // 8192 words  (ends at +24576 < 40960)
static const size_t ZERO1_N  = 65536;            // cnt + fill
static const size_t ZERO2_N  = 41280;            // Ec + Dcv

__device__ __forceinline__ float bfu(unsigned int lo16) {
    return __uint_as_float(lo16 << 16);
}
__device__ __forceinline__ float bfhi(unsigned int w) {
    return __uint_as_float(w & 0xffff0000u);
}
__device__ __forceinline__ float ldf(const void* p, size_t i, bool isbf) {
    return isbf ? bfu((unsigned int)((const unsigned short*)p)[i])
                : ((const float*)p)[i];
}
__device__ __forceinline__ unsigned short f2bf(float v) {
    __hip_bfloat16 h = __float2bfloat16(v);
    return *(unsigned short*)&h;
}

// --- top-k helpers: u64 sortable keys + compare-and-swap networks ---------
__device__ __forceinline__ unsigned long long mkkey(float v, int col) {
    unsigned int bits = __float_as_uint(v);
    unsigned int s = bits ^ (0x80000000u | (unsigned int)((int)bits >> 31));
    return ((unsigned long long)s << 32) | (unsigned int)col;
}
__device__ __forceinline__ void kcas(unsigned long long &a, unsigned long long &b) {
    bool c = b < a;
    unsigned long long t = c ? b : a;
    b = c ? a : b;
    a = t;
}
__device__ __forceinline__ void kmin(unsigned long long &a, unsigned long long b) {
    a = (b < a) ? b : a;
}

// ---------------------------------------------------------------------------
__global__ __launch_bounds__(256) void k_probe(const unsigned int* __restrict__ xw,
                                               int* __restrict__ flag) {
    __shared__ int red[256];
    int t = threadIdx.x;
    int cnt = 0;
    for (int i = t; i < 1024; i += 256) {
        float b = bfu(xw[i] & 0xffffu);
        float ab = fabsf(b);
        if (ab > 9.5e-7f && ab < 1.0e6f) cnt++;
    }
    red[t] = cnt;
    __syncthreads();
    for (int off = 128; off > 0; off >>= 1) {
        if (t < off) red[t] += red[t + off];
        __syncthreads();
    }
    if (t == 0) flag[0] = (red[0] >= 700) ? 1 : 0;
}

__global__ __launch_bounds__(256) void k_zero(float* __restrict__ p, int n) {
    int i = blockIdx.x * 256 + threadIdx.x;
    if (i < n) p[i] = 0.0f;
}

// ---------------------------------------------------------------------------
// R13: one-shot weight split. Wp (64x128) and Th (128x128) -> fp16 h/l
// pairs (lo scaled x2048). Removes per-block cvt VALU + scalar ds_write_u16
// staging from k_proj/k_theta (1024 blocks each re-split the same weights).
// ---------------------------------------------------------------------------
__global__ __launch_bounds__(256) void k_split(const void* __restrict__ Wp,
                                               const void* __restrict__ Th,
                                               const int* __restrict__ flag,
                                               _Float16* __restrict__ WpH,
                                               _Float16* __restrict__ WpL,
                                               _Float16* __restrict__ ThH,
                                               _Float16* __restrict__ ThL) {
    const bool isbf = (flag[0] != 0);
    int i = blockIdx.x * 256 + threadIdx.x;
    if (i < 8192) {
        float v = ldf(Wp, i, isbf);
        _Float16 h = (_Float16)v;
        WpH[i] = h;
        WpL[i] = (_Float16)((v - (float)h) * 2048.0f);
    } else {
        int j = i - 8192;
        float v = ldf(Th, j, isbf);
        _Float16 h = (_Float16)v;
        ThH[j] = h;
        ThL[j] = (_Float16)((v - (float)h) * 2048.0f);
    }
}

// ---------------------------------------------------------------------------
// Kernel 1 (R13): Z = x_flat @ Wp^T + b via fp16-split MFMA; weights staged
// from pre-split WpH/WpL with uint4 loads + ds_write_b128 (was: per-block
// fp32->fp16x2 conversion + scalar u16 LDS writes).
// sq = ||Z||^2 ; Hc = softmax(Z @ C^T) epilogue unchanged.
// ---------------------------------------------------------------------------
__global__ __launch_bounds__(256) void k_proj(const void* __restrict__ x,
                                              const _Float16* __restrict__ WpH,
                                              const _Float16* __restrict__ WpL,
                                              const void* __restrict__ Wpb,
                                              const void* __restrict__ Cm,
                                              const int* __restrict__ flag,
                                              _Float16* __restrict__ Zh,
                                              _Float16* __restrict__ Zl,
                                              float* __restrict__ sqv,
                                              float* __restrict__ Hc) {
    __shared__ __align__(16) _Float16 wps[2][64][72];
    __shared__ __align__(16) _Float16 xsh[2][32][72];
    __shared__ float zs[32][68];
    __shared__ float cs[10][64];

    const bool isbf = (flag[0] != 0);
    int tid = threadIdx.x;
    int bi  = blockIdx.x;
    int bm  = bi >> 5;
    int n0  = (bi & 31) << 5;
    int b   = bm >> 3, m = bm & 7;

    int lane = tid & 63, wave = tid >> 6;
    int m16 = lane & 15, quad = lane >> 4;
    int rh = wave >> 1, ch = wave & 1;

    for (int e = tid; e < 640; e += 256) cs[e >> 6][e & 63] = ldf(Cm, e, isbf);

    f32x4 aH[2], aX[2];
#pragma unroll
    for (int t = 0; t < 2; ++t) {
        aH[t] = (f32x4){0.f, 0.f, 0.f, 0.f};
        aX[t] = (f32x4){0.f, 0.f, 0.f, 0.f};
    }

    for (int kc = 0; kc < 2; ++kc) {
        __syncthreads();
        for (int e = tid; e < 512; e += 256) {
            int p = e >> 3, c = e & 7;
            *(uint4*)&wps[0][p][c * 8] =
                *(const uint4*)(WpH + (size_t)p * 128 + kc * 64 + c * 8);
            *(uint4*)&wps[1][p][c * 8] =
                *(const uint4*)(WpL + (size_t)p * 128 + kc * 64 + c * 8);
        }
        for (int e = tid; e < 2048; e += 256) {
            int r = e >> 6, dk = e & 63;
            float v = ldf(x, (((size_t)b * NNODE + n0 + r) * 8 + m) * DIN + kc * 64 + dk, isbf);
            _Float16 h = (_Float16)v;
            xsh[0][r][dk] = h;
            xsh[1][r][dk] = (_Float16)((v - (float)h) * 2048.0f);
        }
        __syncthreads();
#pragma unroll
        for (int c32 = 0; c32 < 2; ++c32) {
            half8 Ah = *(const half8*)&xsh[0][rh * 16 + m16][c32 * 32 + quad * 8];
            half8 Al = *(const half8*)&xsh[1][rh * 16 + m16][c32 * 32 + quad * 8];
#pragma unroll
            for (int t = 0; t < 2; ++t) {
                int p = ch * 32 + t * 16 + m16;
                half8 Bh = *(const half8*)&wps[0][p][c32 * 32 + quad * 8];
                half8 Bl = *(const half8*)&wps[1][p][c32 * 32 + quad * 8];
                aH[t] = __builtin_amdgcn_mfma_f32_16x16x32_f16(Ah, Bh, aH[t], 0, 0, 0);
                aX[t] = __builtin_amdgcn_mfma_f32_16x16x32_f16(Al, Bh, aX[t], 0, 0, 0);
                aX[t] = __builtin_amdgcn_mfma_f32_16x16x32_f16(Ah, Bl, aX[t], 0, 0, 0);
            }
        }
    }

#pragma unroll
    for (int t = 0; t < 2; ++t) {
        int p = ch * 32 + t * 16 + m16;
        float bias = ldf(Wpb, p, isbf);
#pragma unroll
        for (int r = 0; r < 4; ++r) {
            int row = rh * 16 + quad * 4 + r;
            float v = aH[t][r] + aX[t][r] * (1.0f / 2048.0f) + bias;
            zs[row][p] = v;
            size_t off = ((size_t)bm * NNODE + n0 + row) * 64 + p;
            _Float16 h = (_Float16)v;
            Zh[off] = h;
            Zl[off] = (_Float16)((v - (float)h) * 2048.0f);
        }
    }
    __syncthreads();

    int row = tid >> 3, slot = tid & 7;
    int d0 = slot * 8;
    float sp = 0.f;
#pragma unroll
    for (int dd = 0; dd < 8; ++dd) { float z = zs[row][d0+dd]; sp += z * z; }
#pragma unroll
    for (int mm = 1; mm < 8; mm <<= 1) sp += __shfl_xor(sp, mm, 8);
    size_t g = (size_t)bm * NNODE + n0 + row;
    if (slot == 0) sqv[g] = sp;

    float sc[10];
#pragma unroll
    for (int c = 0; c < 10; ++c) {
        float pa = 0.f;
#pragma unroll
        for (int dd = 0; dd < 8; ++dd) pa += zs[row][d0+dd] * cs[c][d0+dd];
#pragma unroll
        for (int mm = 1; mm < 8; mm <<= 1) pa += __shfl_xor(pa, mm, 8);
        sc[c] = pa;
    }
    float mx = sc[0];
#pragma unroll
    for (int c = 1; c < 10; ++c) mx = fmaxf(mx, sc[c]);
    float ssum = 0.f;
#pragma unroll
    for (int c = 0; c < 10; ++c) { sc[c] = expf(sc[c] - mx); ssum += sc[c]; }
    float inv = 1.0f / ssum;
#pragma unroll
    for (int c = 0; c < 10; ++c)
        if ((c & 7) == slot) Hc[g * 10 + c] = sc[c] * inv;
}

// ---------------------------------------------------------------------------
// Kernel 2 (R13): X_trans = x_flat @ Theta^T + b via fp16-split MFMA.
// R12 fusion REVERTED (measured 87us, latency/atomic-bound). Theta staged
// from pre-split ThH/ThL with uint4 + ds_write_b128.
// ---------------------------------------------------------------------------
__global__ __launch_bounds__(256) void k_theta(const void* __restrict__ x,
                                               const _Float16* __restrict__ ThH,
                                               const _Float16* __restrict__ ThL,
                                               const void* __restrict__ Thb,
                                               const int* __restrict__ flag,
                                               float* __restrict__ Xt) {
    __shared__ __align__(16) _Float16 ths[2][128][72];
    __shared__ __align__(16) _Float16 xsh[2][32][72];

    const bool isbf = (flag[0] != 0);
    int tid = threadIdx.x;
    int bi  = blockIdx.x;
    int bm  = bi >> 5;
    int n0  = (bi & 31) << 5;
    int b   = bm >> 3, m = bm & 7;

    int lane = tid & 63, wave = tid >> 6;
    int m16 = lane & 15, quad = lane >> 4;
    int rh = wave >> 1, ch = wave & 1;   // 2x2 wave grid: rows rh*16, cols ch*64

    f32x4 aH[4], aX[4];
#pragma unroll
    for (int t = 0; t < 4; ++t) {
        aH[t] = (f32x4){0.f, 0.f, 0.f, 0.f};
        aX[t] = (f32x4){0.f, 0.f, 0.f, 0.f};
    }

    for (int kc = 0; kc < 2; ++kc) {
        __syncthreads();
        for (int e = tid; e < 1024; e += 256) {
            int f = e >> 3, c = e & 7;
            *(uint4*)&ths[0][f][c * 8] =
                *(const uint4*)(ThH + (size_t)f * 128 + kc * 64 + c * 8);
            *(uint4*)&ths[1][f][c * 8] =
                *(const uint4*)(ThL + (size_t)f * 128 + kc * 64 + c * 8);
        }
        for (int e = tid; e < 2048; e += 256) {
            int r = e >> 6, dk = e & 63;
            float v = ldf(x, (((size_t)b * NNODE + n0 + r) * 8 + m) * DIN + kc * 64 + dk, isbf);
            _Float16 h = (_Float16)v;
            xsh[0][r][dk] = h;
            xsh[1][r][dk] = (_Float16)((v - (float)h) * 2048.0f);
        }
        __syncthreads();
#pragma unroll
        for (int c32 = 0; c32 < 2; ++c32) {
            half8 Ah = *(const half8*)&xsh[0][rh * 16 + m16][c32 * 32 + quad * 8];
            half8 Al = *(const half8*)&xsh[1][rh * 16 + m16][c32 * 32 + quad * 8];
#pragma unroll
            for (int t = 0; t < 4; ++t) {
                int f = ch * 64 + t * 16 + m16;
                half8 Bh = *(const half8*)&ths[0][f][c32 * 32 + quad * 8];
                half8 Bl = *(const half8*)&ths[1][f][c32 * 32 + quad * 8];
                aH[t] = __builtin_amdgcn_mfma_f32_16x16x32_f16(Ah, Bh, aH[t], 0, 0, 0);
                aX[t] = __builtin_amdgcn_mfma_f32_16x16x32_f16(Al, Bh, aX[t], 0, 0, 0);
                aX[t] = __builtin_amdgcn_mfma_f32_16x16x32_f16(Ah, Bl, aX[t], 0, 0, 0);
            }
        }
    }
#pragma unroll
    for (int t = 0; t < 4; ++t) {
        int f = ch * 64 + t * 16 + m16;
        float bias = ldf(Thb, f, isbf);
        size_t rb = (size_t)bm * NNODE + n0 + rh * 16 + quad * 4;
#pragma unroll
        for (int r = 0; r < 4; ++r) {
            Xt[(rb + r) * 128 + f] = aH[t][r] + aX[t][r] * (1.0f / 2048.0f) + bias;
        }
    }
}

// ---------------------------------------------------------------------------
// Kernel 3 (R13 = exact R10/R3 revert, measured 66us): fused Gram + top-K,
// 32 rows/block, no swizzle (Zh/Zl is L3-resident; R12's swizzle+prefetch
// measured 82us — reverted).
// ---------------------------------------------------------------------------
__global__ __launch_bounds__(256) void k_topk(const _Float16* __restrict__ Zh,
                                              const _Float16* __restrict__ Zl,
                                              const float* __restrict__ sqv,
                                              int* __restrict__ idxo,
                                              int* __restrict__ cnt) {
    __shared__ __align__(16) _Float16 BH[64 * 72];
    __shared__ __align__(16) _Float16 BL[64 * 72];
    __shared__ float    ST[64 * 36];
    __shared__ float    sqt[64];

    int tid = threadIdx.x;
    int bi  = blockIdx.x;
    int bm  = bi >> 5;
    int n0  = (bi & 31) << 5;
    const _Float16* Zhb = Zh + (size_t)bm * NNODE * 64;
    const _Float16* Zlb = Zl + (size_t)bm * NNODE * 64;

    int lane = tid & 63, wave = tid >> 6;
    int m16 = lane & 15, quad = lane >> 4;

    half8 ah0, ah1, al0, al1, ah0b, ah1b, al0b, al1b;
    {
        size_t ab = (size_t)(n0 + m16) * 64 + quad * 8;
        ah0 = *(const half8*)(Zhb + ab);
        ah1 = *(const half8*)(Zhb + ab + 32);
        al0 = *(const half8*)(Zlb + ab);
        al1 = *(const half8*)(Zlb + ab + 32);
        size_t ab2 = ab + 16 * 64;
        ah0b = *(const half8*)(Zhb + ab2);
        ah1b = *(const half8*)(Zhb + ab2 + 32);
        al0b = *(const half8*)(Zlb + ab2);
        al1b = *(const half8*)(Zlb + ab2 + 32);
    }

    unsigned long long keys[10];
#pragma unroll
    for (int j = 0; j < 10; ++j) keys[j] = ~0ULL;

    int srow  = tid >> 3;    // 0..31: this thread's row
    int sslot = tid & 7;     // 8 threads per row

    for (int t = 0; t < 16; ++t) {
        int j0 = t << 6;
        for (int e = tid; e < 512; e += 256) {
            int col = e >> 3, kc = e & 7;
            *(uint4*)&BH[col * 72 + kc * 8] =
                *(const uint4*)(Zhb + (size_t)(j0 + col) * 64 + kc * 8);
            *(uint4*)&BL[col * 72 + kc * 8] =
                *(const uint4*)(Zlb + (size_t)(j0 + col) * 64 + kc * 8);
        }
        if (tid < 64) sqt[tid] = sqv[(size_t)bm * NNODE + j0 + tid];
        __syncthreads();

        {
            int cl = wave * 16 + m16;
            const _Float16* pb = &BH[cl * 72 + quad * 8];
            const _Float16* pl = &BL[cl * 72 + quad * 8];
            half8 bh0 = *(const half8*)pb;
            half8 bh1 = *(const half8*)(pb + 32);
            half8 bl0 = *(const half8*)pl;
            half8 bl1 = *(const half8*)(pl + 32);
            float sqc = sqt[cl];

            f32x4 acc  = {0.f, 0.f, 0.f, 0.f};
            f32x4 accx = {0.f, 0.f, 0.f, 0.f};
            acc  = __builtin_amdgcn_mfma_f32_16x16x32_f16(ah0, bh0, acc, 0, 0, 0);
            acc  = __builtin_amdgcn_mfma_f32_16x16x32_f16(ah1, bh1, acc, 0, 0, 0);
            accx = __builtin_amdgcn_mfma_f32_16x16x32_f16(al0, bh0, accx, 0, 0, 0);
            accx = __builtin_amdgcn_mfma_f32_16x16x32_f16(ah0, bl0, accx, 0, 0, 0);
            accx = __builtin_amdgcn_mfma_f32_16x16x32_f16(al1, bh1, accx, 0, 0, 0);
            accx = __builtin_amdgcn_mfma_f32_16x16x32_f16(ah1, bl1, accx, 0, 0, 0);
            f32x4 sc;
#pragma unroll
            for (int r = 0; r < 4; ++r) {
                float g = acc[r] + accx[r] * (1.0f / 2048.0f);
                sc[r] = fmaf(-2.0f, g, sqc);
            }
            *(f32x4*)&ST[cl * 36 + quad * 4] = sc;

            f32x4 accB  = {0.f, 0.f, 0.f, 0.f};
            f32x4 accxB = {0.f, 0.f, 0.f, 0.f};
            accB  = __builtin_amdgcn_mfma_f32_16x16x32_f16(ah0b, bh0, accB, 0, 0, 0);
            accB  = __builtin_amdgcn_mfma_f32_16x16x32_f16(ah1b, bh1, accB, 0, 0, 0);
            accxB = __builtin_amdgcn_mfma_f32_16x16x32_f16(al0b, bh0, accxB, 0, 0, 0);
            accxB = __builtin_amdgcn_mfma_f32_16x16x32_f16(ah0b, bl0, accxB, 0, 0, 0);
            accxB = __builtin_amdgcn_mfma_f32_16x16x32_f16(al1b, bh1, accxB, 0, 0, 0);
            accxB = __builtin_amdgcn_mfma_f32_16x16x32_f16(ah1b, bl1, accxB, 0, 0, 0);
#pragma unroll
            for (int r = 0; r < 4; ++r) {
                float g = accB[r] + accxB[r] * (1.0f / 2048.0f);
                sc[r] = fmaf(-2.0f, g, sqc);
            }
            *(f32x4*)&ST[cl * 36 + 16 + quad * 4] = sc;
        }
        __syncthreads();

        unsigned long long b0 = mkkey(ST[(sslot     ) * 36 + srow], j0 + sslot);
        unsigned long long b1 = mkkey(ST[(sslot +  8) * 36 + srow], j0 + sslot + 8);
        unsigned long long b2 = mkkey(ST[(sslot + 16) * 36 + srow], j0 + sslot + 16);
        unsigned long long b3 = mkkey(ST[(sslot + 24) * 36 + srow], j0 + sslot + 24);
        unsigned long long b4 = mkkey(ST[(sslot + 32) * 36 + srow], j0 + sslot + 32);
        unsigned long long b5 = mkkey(ST[(sslot + 40) * 36 + srow], j0 + sslot + 40);
        unsigned long long b6 = mkkey(ST[(sslot + 48) * 36 + srow], j0 + sslot + 48);
        unsigned long long b7 = mkkey(ST[(sslot + 56) * 36 + srow], j0 + sslot + 56);

        // --- sort-8 ascending: Batcher odd-even mergesort (19 CAS, depth 6)
        kcas(b0, b1); kcas(b2, b3); kcas(b4, b5); kcas(b6, b7);
        kcas(b0, b2); kcas(b1, b3); kcas(b4, b6); kcas(b5, b7);
        kcas(b1, b2); kcas(b5, b6);
        kcas(b0, b4); kcas(b1, b5); kcas(b2, b6); kcas(b3, b7);
        kcas(b2, b4); kcas(b3, b5);
        kcas(b1, b2); kcas(b3, b4); kcas(b5, b6);

        // --- lowest-10 of (sorted keys[10]) U (sorted b0..b7)
        kmin(keys[2], b7); kmin(keys[3], b6); kmin(keys[4], b5); kmin(keys[5], b4);
        kmin(keys[6], b3); kmin(keys[7], b2); kmin(keys[8], b1); kmin(keys[9], b0);

        // --- re-sort: bitonic merge-16 restricted to 10 (15 CAS, depth 4)
        kcas(keys[0], keys[8]); kcas(keys[1], keys[9]);
        kcas(keys[2], keys[6]); kcas(keys[3], keys[7]);
        kcas(keys[4], keys[8]); kcas(keys[5], keys[9]);
        kcas(keys[2], keys[4]); kcas(keys[3], keys[5]);
        kcas(keys[6], keys[8]); kcas(keys[7], keys[9]);
        kcas(keys[0], keys[1]); kcas(keys[2], keys[3]);
        kcas(keys[4], keys[5]); kcas(keys[6], keys[7]); kcas(keys[8], keys[9]);
    }

    size_t gr = (size_t)bm * NNODE + n0 + srow;
    for (int it = 0; it < 10; ++it) {
        unsigned long long mine = keys[0];
        unsigned long long best = mine;
#pragma unroll
        for (int mm = 1; mm < 8; mm <<= 1) {
            unsigned long long o = __shfl_xor(best, mm, 8);
            if (o < best) best = o;
        }
        if (best == mine) {
#pragma unroll
            for (int j = 0; j < 9; ++j) keys[j] = keys[j+1];
            keys[9] = ~0ULL;
            int col = (int)(best & 0xFFFFFFFFu);
            idxo[gr * KNB + it] = col;
            atomicAdd(&cnt[bm * NNODE + col], 1);
        }
    }
}

// ---------------------------------------------------------------------------
// CSR build (unchanged)
// ---------------------------------------------------------------------------
__global__ __launch_bounds__(256) void k_scan(const int* __restrict__ cnt,
                                              int* __restrict__ offs) {
    __shared__ int part[256];
    int bm = blockIdx.x, t = threadIdx.x;
    int base = bm * 1024 + t * 4;
    int c0 = cnt[base], c1 = cnt[base+1], c2 = cnt[base+2], c3 = cnt[base+3];
    int ps = c0 + c1 + c2 + c3;
    part[t] = ps;
    __syncthreads();
    for (int off = 1; off < 256; off <<= 1) {
        int add = (t >= off) ? part[t - off] : 0;
        __syncthreads();
        part[t] += add;
        __syncthreads();
    }
    int e0 = part[t] - ps;
    int gb = bm * (NNODE * KNB);
    offs[base]   = gb + e0;
    offs[base+1] = gb + e0 + c0;
    offs[base+2] = gb + e0 + c0 + c1;
    offs[base+3] = gb + e0 + c0 + c1 + c2;
}

__global__ __launch_bounds__(256) void k_fill(const int* __restrict__ idxb,
                                              const int* __restrict__ offs,
                                              int* __restrict__ fill,
                                              int* __restrict__ adj) {
    int i = blockIdx.x * 256 + threadIdx.x;
    int g = i / 10;
    int bm = g >> 10;
    int e  = idxb[i];
    int eg = (bm << 10) + e;
    int pos = atomicAdd(&fill[eg], 1);
    adj[offs[eg] + pos] = g;
}

// ---------------------------------------------------------------------------
// kNN edge gather v3 (R11, unchanged): XCD swizzle + 16-wide batch gather.
// ---------------------------------------------------------------------------
__global__ __launch_bounds__(256) void k_edge(const float* __restrict__ Xt,
                                              const int* __restrict__ offs,
                                              const int* __restrict__ cnt,
                                              const int* __restrict__ adj,
                                              unsigned short* __restrict__ Ek) {
    int tid = threadIdx.x;
    int bi  = blockIdx.x;
    int swz = (bi & 7) * 512 + (bi >> 3);
    int e = swz * 8 + (tid >> 5);
    int l = tid & 31;
    int start = offs[e];
    int num = cnt[e];
    float4 acc = {0.f, 0.f, 0.f, 0.f};
    if (num > 0) {
        int nm1 = num - 1;
        int gidx[16];
#pragma unroll
        for (int j = 0; j < 16; ++j) {
            int jj = (j < nm1) ? j : nm1;
            gidx[j] = adj[start + jj];
        }
#pragma unroll
        for (int j = 0; j < 16; ++j) {
            float4 a = *(const float4*)(Xt + (size_t)gidx[j] * 128 + l * 4);
            float w = (j < num) ? 1.0f : 0.0f;
            acc.x = fmaf(w, a.x, acc.x);
            acc.y = fmaf(w, a.y, acc.y);
            acc.z = fmaf(w, a.z, acc.z);
            acc.w = fmaf(w, a.w, acc.w);
        }
        int i = 16;
        for (; i + 1 < num; i += 2) {
            int g0 = adj[start + i];
            int g1 = adj[start + i + 1];
            float4 a = *(const float4*)(Xt + (size_t)g0 * 128 + l * 4);
            float4 b = *(const float4*)(Xt + (size_t)g1 * 128 + l * 4);
            acc.x += a.x + b.x; acc.y += a.y + b.y;
            acc.z += a.z + b.z; acc.w += a.w + b.w;
        }
        if (i < num) {
            int g0 = adj[start + i];
            float4 a = *(const float4*)(Xt + (size_t)g0 * 128 + l * 4);
            acc.x += a.x; acc.y += a.y; acc.z += a.z; acc.w += a.w;
        }
    }
    float scale = (num > 0) ? 1.0f / (float)num : 0.0f;
    ushort4 o;
    o.x = f2bf(acc.x * scale);
    o.y = f2bf(acc.y * scale);
    o.z = f2bf(acc.z * scale);
    o.w = f2bf(acc.w * scale);
    *(ushort4*)(Ek + (size_t)e * 128 + l * 4) = o;
}

// ---------------------------------------------------------------------------
// Cluster edges (restored R3 standalone — R12 fusion reverted)
// ---------------------------------------------------------------------------
__global__ __launch_bounds__(256) void k_clus(const float* __restrict__ Xt,
                                              const float* __restrict__ Hc,
                                              float* __restrict__ Ec,
                                              float* __restrict__ Dcv) {
    int tid = threadIdx.x;
    int bm = blockIdx.x >> 3;
    int ch = blockIdx.x & 7;
    int f = tid & 127;
    int h = tid >> 7;
    int c0 = h * 5;
    float acc[5]  = {0.f,0.f,0.f,0.f,0.f};
    float dacc[5] = {0.f,0.f,0.f,0.f,0.f};
    int n0 = ch * 128;
    for (int n = n0; n < n0 + 128; ++n) {
        size_t g = (size_t)bm * NNODE + n;
        float xv = Xt[g * 128 + f];
#pragma unroll
        for (int j = 0; j < 5; ++j) {
            float hv = Hc[g * 10 + c0 + j];
            acc[j]  += hv * xv;
            dacc[j] += hv;
        }
    }
#pragma unroll
    for (int j = 0; j < 5; ++j)
        atomicAdd(&Ec[((size_t)bm * 10 + c0 + j) * 128 + f], acc[j]);
    if (f == 0) {
#pragma unroll
        for (int j = 0; j < 5; ++j) atomicAdd(&Dcv[bm * 10 + c0 + j], dacc[j]);
    }
}

__global__ __launch_bounds__(256) void k_escale(float* __restrict__ Ec,
                                                const float* __restrict__ Dcv) {
    int i = blockIdx.x * 256 + threadIdx.x;
    float d = Dcv[i >> 7];
    Ec[i] = (d > 0.f) ? Ec[i] / d : 0.f;
}

// ---------------------------------------------------------------------------
// Final v3 (R11, unchanged): 32 threads/node, XCD swizzle.
// ---------------------------------------------------------------------------
__global__ __launch_bounds__(256) void k_final(const unsigned short* __restrict__ Ek,
                                               const float* __restrict__ Ec,
                                               const float* __restrict__ Hc,
                                               const int* __restrict__ idxb,
                                               float* __restrict__ out) {
    int tid = threadIdx.x;
    int bi  = blockIdx.x;
    int swz = (bi & 7) * 512 + (bi >> 3);
    int g = swz * 8 + (tid >> 5);
    int l = tid & 31;
    int bm = g >> 10, n = g & 1023;
    const int* ip = idxb + (size_t)g * 10;
    const unsigned short* ekb = Ek + ((size_t)bm << 10) * 128 + l * 4;

    float4 acc = {0.f, 0.f, 0.f, 0.f};
#pragma unroll
    for (int k = 0; k < 10; k += 2) {
        int e0 = ip[k], e1 = ip[k + 1];
        ushort4 u0 = *(const ushort4*)(ekb + (size_t)e0 * 128);
        ushort4 u1 = *(const ushort4*)(ekb + (size_t)e1 * 128);
        acc.x += bfu(u0.x) + bfu(u1.x);
        acc.y += bfu(u0.y) + bfu(u1.y);
        acc.z += bfu(u0.z) + bfu(u1.z);
        acc.w += bfu(u0.w) + bfu(u1.w);
    }
    const float* hp  = Hc + (size_t)g * 10;
    const float* ecp = Ec + (size_t)bm * 10 * 128 + l * 4;
#pragma unroll
    for (int c = 0; c < 10; ++c) {
        float hv = hp[c];
        float4 ec = *(const float4*)(ecp + c * 128);
        acc.x += hv * ec.x; acc.y += hv * ec.y;
        acc.z += hv * ec.z; acc.w += hv * ec.w;
    }
    float4 r;
    r.x = acc.x * (1.0f / 11.0f);
    r.y = acc.y * (1.0f / 11.0f);
    r.z = acc.z * (1.0f / 11.0f);
    r.w = acc.w * (1.0f / 11.0f);
    r.x = (r.x > 0.f) ? r.x : expm1f(r.x);
    r.y = (r.y > 0.f) ? r.y : expm1f(r.y);
    r.z = (r.z > 0.f) ? r.z : expm1f(r.z);
    r.w = (r.w > 0.f) ? r.w : expm1f(r.w);
    int b = bm >> 3, m = bm & 7;
    *(float4*)(out + (((size_t)b * NNODE + n) * 8 + m) * 128 + l * 4) = r;
}

// ---------------------------------------------------------------------------
extern "C" void kernel_launch(void* const* d_in, const int* in_sizes, int n_in,
                              void* d_out, int out_size, void* d_ws, size_t ws_size,
                              hipStream_t stream) {
    const void* x   = d_in[0];
    const void* Wp  = d_in[1];
    const void* Wpb = d_in[2];
    const void* Cm  = d_in[3];
    const void* Th  = d_in[4];
    const void* Thb = d_in[5];
    float* ws = (float*)d_ws;

    if (ws_size < OFF_END * sizeof(float)) return;

    _Float16* Zh = (_Float16*)(ws + OFF_Z);
    _Float16* Zl = (_Float16*)(ws + OFF_Z + 1048576);
    float* sqv  = ws + OFF_SQ;
    float* Hc   = ws + OFF_HC;
    int*   idxb = (int*)(ws + OFF_IDX);
    int*   cnt  = (int*)(ws + OFF_CNT);
    int*   fill = (int*)(ws + OFF_FILL);
    float* Ec   = ws + OFF_EC;
    float* Dcv  = ws + OFF_DCV;
    int*   offs = (int*)(ws + OFF_OFFS);
    int*   adj  = (int*)(ws + OFF_ADJ);
    int*   flag = (int*)(ws + OFF_FLAG);
    _Float16* WpH = (_Float16*)(ws + OFF_WPH);
    _Float16* WpL = (_Float16*)(ws + OFF_WPL);
    _Float16* ThH = (_Float16*)(ws + OFF_THH);
    _Float16* ThL = (_Float16*)(ws + OFF_THL);
    unsigned short* Ek = (unsigned short*)(ws + OFF_Z);  // overlays dead Zh/Zl
    float* Xt  = (float*)d_out;
    float* out = (float*)d_out;

    k_probe <<<1, 256, 0, stream>>>((const unsigned int*)x, flag);
    k_zero  <<<256, 256, 0, stream>>>(ws + OFF_CNT, (int)ZERO1_N);   // cnt + fill
    k_split <<<96,  256, 0, stream>>>(Wp, Th, flag, WpH, WpL, ThH, ThL);
    k_proj  <<<1024, 256, 0, stream>>>(x, WpH, WpL, Wpb, Cm, flag, Zh, Zl, sqv, Hc);
    k_topk  <<<1024, 256, 0, stream>>>(Zh, Zl, sqv, idxb, cnt);
    k_scan  <<<32,   256, 0, stream>>>(cnt, offs);
    k_fill  <<<1280, 256, 0, stream>>>(idxb, offs, fill, adj);
    k_theta <<<1024, 256, 0, stream>>>(x, ThH, ThL, Thb, flag, Xt);
    k_zero  <<<162,  256, 0, stream>>>(ws + OFF_EC, (int)ZERO2_N);   // Ec + Dcv (weights now dead)
    k_edge  <<<4096, 256, 0, stream>>>(Xt, offs, cnt, adj, Ek);
    k_clus  <<<256,  256, 0, stream>>>(Xt, Hc, Ec, Dcv);
    k_escale<<<160,  256, 0, stream>>>(Ec, Dcv);
    k_final <<<4096, 256, 0, stream>>>(Ek, Ec, Hc, idxb, out);
}